// Round 1
// baseline (176.868 us; speedup 1.0000x reference)
//
#include <hip/hip_runtime.h>

#define T_ 4
#define C_ 512
#define B_ 8
#define HW_ 1024
#define W_ 32
#define HP_ 28
#define EPS_ 1e-5f
#define CCH 16   // channels per diff2 block

// ---------------- Kernel 1: per-(t,c) stats -> coefficients ----------------
// coef[t*C+c] = (a_l, a_r, off, 0) with a_l=g*s_l, a_r=g*s_r,
// off=g*(s_l*mu_l - s_r*mu_r);  beta cancels in (l-r).
__global__ __launch_bounds__(256) void stats_kernel(const float* __restrict__ L,
                                                    const float* __restrict__ R,
                                                    const float* __restrict__ gamma,
                                                    float4* __restrict__ coef) {
    const int tc = blockIdx.x;          // t*C_ + c
    const int tid = threadIdx.x;
    const int t = tc >> 9;
    const int c = tc & (C_ - 1);
    const float4* L4 = (const float4*)L;
    const float4* R4 = (const float4*)R;

    float sl = 0.f, ql = 0.f, sr = 0.f, qr = 0.f;
#pragma unroll
    for (int b = 0; b < B_; ++b) {
        size_t base4 = ((size_t)(b * T_ + t) * C_ + c) * (HW_ / 4);
        float4 vl = L4[base4 + tid];
        float4 vr = R4[base4 + tid];
        sl += vl.x + vl.y + vl.z + vl.w;
        ql += vl.x * vl.x + vl.y * vl.y + vl.z * vl.z + vl.w * vl.w;
        sr += vr.x + vr.y + vr.z + vr.w;
        qr += vr.x * vr.x + vr.y * vr.y + vr.z * vr.z + vr.w * vr.w;
    }

    __shared__ float red[4][256];
    red[0][tid] = sl; red[1][tid] = ql; red[2][tid] = sr; red[3][tid] = qr;
    __syncthreads();
    for (int s = 128; s > 0; s >>= 1) {
        if (tid < s) {
            red[0][tid] += red[0][tid + s];
            red[1][tid] += red[1][tid + s];
            red[2][tid] += red[2][tid + s];
            red[3][tid] += red[3][tid + s];
        }
        __syncthreads();
    }
    if (tid == 0) {
        const float inv = 1.0f / (float)(B_ * HW_);
        float mul = red[0][0] * inv, mur = red[2][0] * inv;
        float varl = red[1][0] * inv - mul * mul;
        float varr = red[3][0] * inv - mur * mur;
        float s_l = rsqrtf(varl + EPS_);
        float s_r = rsqrtf(varr + EPS_);
        float g = gamma[c];
        coef[tc] = make_float4(g * s_l, g * s_r, g * (s_l * mul - s_r * mur), 0.f);
    }
}

// ---------------- Kernel 2: diff2[b,t,h,w] += sum_c (a_l x_l - a_r x_r - off)^2
__global__ __launch_bounds__(256) void diff2_kernel(const float* __restrict__ L,
                                                    const float* __restrict__ R,
                                                    const float4* __restrict__ coef,
                                                    float* __restrict__ diff2) {
    const int chunk = blockIdx.x;   // 0..C_/CCH-1
    const int bt = blockIdx.y;      // b*T_ + t
    const int t = bt & (T_ - 1);
    const int tid = threadIdx.x;
    const int c0 = chunk * CCH;

    __shared__ float4 cf[CCH];
    if (tid < CCH) cf[tid] = coef[t * C_ + c0 + tid];
    __syncthreads();

    const float4* L4 = (const float4*)L;
    const float4* R4 = (const float4*)R;
    const size_t base4 = ((size_t)bt * C_ + c0) * (HW_ / 4);

    float a0 = 0.f, a1 = 0.f, a2 = 0.f, a3 = 0.f;
#pragma unroll
    for (int cc = 0; cc < CCH; ++cc) {
        float4 k = cf[cc];
        float4 vl = L4[base4 + cc * (HW_ / 4) + tid];
        float4 vr = R4[base4 + cc * (HW_ / 4) + tid];
        float d0 = k.x * vl.x - k.y * vr.x - k.z;
        float d1 = k.x * vl.y - k.y * vr.y - k.z;
        float d2 = k.x * vl.z - k.y * vr.z - k.z;
        float d3 = k.x * vl.w - k.y * vr.w - k.z;
        a0 += d0 * d0; a1 += d1 * d1; a2 += d2 * d2; a3 += d3 * d3;
    }
    float* o = diff2 + (size_t)bt * HW_ + tid * 4;
    atomicAdd(o + 0, a0);
    atomicAdd(o + 1, a1);
    atomicAdd(o + 2, a2);
    atomicAdd(o + 3, a3);
}

// ---------------- Kernel 3: 5x5 window sums, sqrt, max, argmin --------------
// out layout (all f32): [0,32) asymmetry_values, [32,96) coords (x,y) pairs,
// [96, 96+32*784) heatmap.
__global__ __launch_bounds__(256) void finalize_kernel(const float* __restrict__ diff2,
                                                       float* __restrict__ out) {
    const int bt = blockIdx.x;
    const int tid = threadIdx.x;
    __shared__ float d[HW_];
    __shared__ float rowsum[32][HP_];
    __shared__ float rv[256];
    __shared__ int   ri[256];
    __shared__ float rmax[256];

    ((float4*)d)[tid] = ((const float4*)(diff2 + (size_t)bt * HW_))[tid];
    __syncthreads();

    // horizontal 5-window sums: rowsum[h][w], h in [0,32), w in [0,28)
    for (int i = tid; i < 32 * HP_; i += 256) {
        int h = i / HP_, w = i % HP_;
        const float* row = d + h * W_ + w;
        rowsum[h][w] = row[0] + row[1] + row[2] + row[3] + row[4];
    }
    __syncthreads();

    float lmax = -1e30f, lmin = 1e30f;
    int lidx = 0;
    for (int i = tid; i < HP_ * HP_; i += 256) {
        int hh = i / HP_, w = i % HP_;
        float s = rowsum[hh][w] + rowsum[hh + 1][w] + rowsum[hh + 2][w] +
                  rowsum[hh + 3][w] + rowsum[hh + 4][w];
        float hm = sqrtf(s * (1.0f / 25.0f));
        out[96 + (size_t)bt * (HP_ * HP_) + i] = hm;
        lmax = fmaxf(lmax, hm);
        if (hm < lmin) { lmin = hm; lidx = i; }  // i increasing -> first-min
    }
    rv[tid] = lmin; ri[tid] = lidx; rmax[tid] = lmax;
    __syncthreads();
    for (int s = 128; s > 0; s >>= 1) {
        if (tid < s) {
            float ov = rv[tid + s]; int oi = ri[tid + s];
            if (ov < rv[tid] || (ov == rv[tid] && oi < ri[tid])) { rv[tid] = ov; ri[tid] = oi; }
            rmax[tid] = fmaxf(rmax[tid], rmax[tid + s]);
        }
        __syncthreads();
    }
    if (tid == 0) {
        out[bt] = rmax[0];
        int idx = ri[0];
        out[32 + 2 * bt + 0] = (float)(idx % HP_);
        out[32 + 2 * bt + 1] = (float)(idx / HP_);
    }
}

extern "C" void kernel_launch(void* const* d_in, const int* in_sizes, int n_in,
                              void* d_out, int out_size, void* d_ws, size_t ws_size,
                              hipStream_t stream) {
    const float* L = (const float*)d_in[0];
    const float* R = (const float*)d_in[1];
    const float* gamma = (const float*)d_in[2];
    // d_in[3] = beta: cancels algebraically in (l - r), unused.
    float* out = (float*)d_out;

    float4* coef = (float4*)d_ws;                       // 2048 float4 = 32 KB
    float* diff2 = (float*)d_ws + 4 * (T_ * C_);        // 32*1024 floats = 128 KB

    hipMemsetAsync(diff2, 0, (size_t)(B_ * T_) * HW_ * sizeof(float), stream);
    stats_kernel<<<T_ * C_, 256, 0, stream>>>(L, R, gamma, coef);
    diff2_kernel<<<dim3(C_ / CCH, B_ * T_), 256, 0, stream>>>(L, R, coef, diff2);
    finalize_kernel<<<B_ * T_, 256, 0, stream>>>(diff2, out);
}

// Round 2
// 171.352 us; speedup vs baseline: 1.0322x; 1.0322x over previous
//
#include <hip/hip_runtime.h>

#define T_ 4
#define C_ 512
#define B_ 8
#define HW_ 1024
#define W_ 32
#define HP_ 28
#define EPS_ 1e-5f
#define CCH 16                    // channels per diff2 block
#define NCHUNK (C_ / CCH)         // 32

// ---------------- Kernel 1: per-(t,c) stats -> coefficients ----------------
// coef[t*C+c] = (a_l, a_r, off, 0) with a_l=g*s_l, a_r=g*s_r,
// off=g*(s_l*mu_l - s_r*mu_r);  beta cancels in (l-r).
// One block per (t,c); wave-shuffle reduce, single barrier, no atomics.
__global__ __launch_bounds__(256) void stats_kernel(const float* __restrict__ L,
                                                    const float* __restrict__ R,
                                                    const float* __restrict__ gamma,
                                                    float4* __restrict__ coef) {
    const int tc = blockIdx.x;          // t*C_ + c
    const int tid = threadIdx.x;
    const int t = tc >> 9;
    const int c = tc & (C_ - 1);
    const float4* L4 = (const float4*)L;
    const float4* R4 = (const float4*)R;

    float sl = 0.f, ql = 0.f, sr = 0.f, qr = 0.f;
#pragma unroll
    for (int b = 0; b < B_; ++b) {
        size_t base4 = ((size_t)(b * T_ + t) * C_ + c) * (HW_ / 4);
        float4 vl = L4[base4 + tid];
        float4 vr = R4[base4 + tid];
        sl += vl.x + vl.y + vl.z + vl.w;
        ql += vl.x * vl.x + vl.y * vl.y + vl.z * vl.z + vl.w * vl.w;
        sr += vr.x + vr.y + vr.z + vr.w;
        qr += vr.x * vr.x + vr.y * vr.y + vr.z * vr.z + vr.w * vr.w;
    }

    // intra-wave butterfly reduce (64 lanes)
#pragma unroll
    for (int off = 32; off > 0; off >>= 1) {
        sl += __shfl_down(sl, off);
        ql += __shfl_down(ql, off);
        sr += __shfl_down(sr, off);
        qr += __shfl_down(qr, off);
    }

    __shared__ float red[4][4];
    const int wave = tid >> 6, lane = tid & 63;
    if (lane == 0) {
        red[0][wave] = sl; red[1][wave] = ql;
        red[2][wave] = sr; red[3][wave] = qr;
    }
    __syncthreads();
    if (tid == 0) {
        float S  = red[0][0] + red[0][1] + red[0][2] + red[0][3];
        float Q  = red[1][0] + red[1][1] + red[1][2] + red[1][3];
        float Sr = red[2][0] + red[2][1] + red[2][2] + red[2][3];
        float Qr = red[3][0] + red[3][1] + red[3][2] + red[3][3];
        const float inv = 1.0f / (float)(B_ * HW_);
        float mul = S * inv, mur = Sr * inv;
        float varl = Q * inv - mul * mul;
        float varr = Qr * inv - mur * mur;
        float s_l = rsqrtf(varl + EPS_);
        float s_r = rsqrtf(varr + EPS_);
        float g = gamma[c];
        coef[tc] = make_float4(g * s_l, g * s_r, g * (s_l * mul - s_r * mur), 0.f);
    }
}

// ------- Kernel 2: partial diff2 per channel-chunk, plain stores (no atomics)
// part[chunk][bt][hw] = sum_{c in chunk} (a_l x_l - a_r x_r - off)^2
__global__ __launch_bounds__(256) void diff2_kernel(const float* __restrict__ L,
                                                    const float* __restrict__ R,
                                                    const float4* __restrict__ coef,
                                                    float4* __restrict__ part4) {
    const int chunk = blockIdx.x;   // 0..NCHUNK-1
    const int bt = blockIdx.y;      // b*T_ + t
    const int t = bt & (T_ - 1);
    const int tid = threadIdx.x;
    const int c0 = chunk * CCH;

    __shared__ float4 cf[CCH];
    if (tid < CCH) cf[tid] = coef[t * C_ + c0 + tid];
    __syncthreads();

    const float4* L4 = (const float4*)L;
    const float4* R4 = (const float4*)R;
    const size_t base4 = ((size_t)bt * C_ + c0) * (HW_ / 4);

    float a0 = 0.f, a1 = 0.f, a2 = 0.f, a3 = 0.f;
#pragma unroll
    for (int cc = 0; cc < CCH; ++cc) {
        float4 k = cf[cc];
        float4 vl = L4[base4 + cc * (HW_ / 4) + tid];
        float4 vr = R4[base4 + cc * (HW_ / 4) + tid];
        float d0 = k.x * vl.x - k.y * vr.x - k.z;
        float d1 = k.x * vl.y - k.y * vr.y - k.z;
        float d2 = k.x * vl.z - k.y * vr.z - k.z;
        float d3 = k.x * vl.w - k.y * vr.w - k.z;
        a0 += d0 * d0; a1 += d1 * d1; a2 += d2 * d2; a3 += d3 * d3;
    }
    part4[((size_t)chunk * (B_ * T_) + bt) * (HW_ / 4) + tid] =
        make_float4(a0, a1, a2, a3);
}

// ---------------- Kernel 3: sum partials, 5x5 windows, sqrt, max, argmin ----
// out layout (all f32): [0,32) asymmetry_values, [32,96) coords (x,y) pairs,
// [96, 96+32*784) heatmap.
__global__ __launch_bounds__(256) void finalize_kernel(const float4* __restrict__ part4,
                                                       float* __restrict__ out) {
    const int bt = blockIdx.x;
    const int tid = threadIdx.x;
    __shared__ float d[HW_];
    __shared__ float rowsum[32][HP_];
    __shared__ float rv[256];
    __shared__ int   ri[256];
    __shared__ float rmax[256];

    float4 s = make_float4(0.f, 0.f, 0.f, 0.f);
#pragma unroll
    for (int ch = 0; ch < NCHUNK; ++ch) {
        float4 v = part4[((size_t)ch * (B_ * T_) + bt) * (HW_ / 4) + tid];
        s.x += v.x; s.y += v.y; s.z += v.z; s.w += v.w;
    }
    ((float4*)d)[tid] = s;
    __syncthreads();

    // horizontal 5-window sums: rowsum[h][w], h in [0,32), w in [0,28)
    for (int i = tid; i < 32 * HP_; i += 256) {
        int h = i / HP_, w = i % HP_;
        const float* row = d + h * W_ + w;
        rowsum[h][w] = row[0] + row[1] + row[2] + row[3] + row[4];
    }
    __syncthreads();

    float lmax = -1e30f, lmin = 1e30f;
    int lidx = 0;
    for (int i = tid; i < HP_ * HP_; i += 256) {
        int hh = i / HP_, w = i % HP_;
        float ws = rowsum[hh][w] + rowsum[hh + 1][w] + rowsum[hh + 2][w] +
                   rowsum[hh + 3][w] + rowsum[hh + 4][w];
        float hm = sqrtf(ws * (1.0f / 25.0f));
        out[96 + (size_t)bt * (HP_ * HP_) + i] = hm;
        lmax = fmaxf(lmax, hm);
        if (hm < lmin) { lmin = hm; lidx = i; }  // i increasing -> first-min
    }
    rv[tid] = lmin; ri[tid] = lidx; rmax[tid] = lmax;
    __syncthreads();
    for (int st = 128; st > 0; st >>= 1) {
        if (tid < st) {
            float ov = rv[tid + st]; int oi = ri[tid + st];
            if (ov < rv[tid] || (ov == rv[tid] && oi < ri[tid])) { rv[tid] = ov; ri[tid] = oi; }
            rmax[tid] = fmaxf(rmax[tid], rmax[tid + st]);
        }
        __syncthreads();
    }
    if (tid == 0) {
        out[bt] = rmax[0];
        int idx = ri[0];
        out[32 + 2 * bt + 0] = (float)(idx % HP_);
        out[32 + 2 * bt + 1] = (float)(idx / HP_);
    }
}

extern "C" void kernel_launch(void* const* d_in, const int* in_sizes, int n_in,
                              void* d_out, int out_size, void* d_ws, size_t ws_size,
                              hipStream_t stream) {
    const float* L = (const float*)d_in[0];
    const float* R = (const float*)d_in[1];
    const float* gamma = (const float*)d_in[2];
    // d_in[3] = beta: cancels algebraically in (l - r), unused.
    float* out = (float*)d_out;

    // ws layout: coef 2048 float4 (32 KB) | partials 32*32*1024 f32 (4 MB)
    float4* coef = (float4*)d_ws;
    float4* part4 = (float4*)((char*)d_ws + 4 * sizeof(float4) * (T_ * C_) / 4 * 4);
    part4 = (float4*)((char*)d_ws + sizeof(float4) * (T_ * C_));

    stats_kernel<<<T_ * C_, 256, 0, stream>>>(L, R, gamma, coef);
    diff2_kernel<<<dim3(NCHUNK, B_ * T_), 256, 0, stream>>>(L, R, coef, part4);
    finalize_kernel<<<B_ * T_, 256, 0, stream>>>(part4, out);
}

// Round 9
// 170.881 us; speedup vs baseline: 1.0350x; 1.0028x over previous
//
#include <hip/hip_runtime.h>

#define T_ 4
#define C_ 512
#define B_ 8
#define HW_ 1024
#define W_ 32
#define HP_ 28
#define EPS_ 1e-5f
#define CCH 16                    // channels per diff2 block
#define NCHUNK (C_ / CCH)         // 32
#define NBT (B_ * T_)             // 32
#define NROWS (B_ * T_ * C_)      // 16384 rows of 1024 floats

// ---------------- Kernel 1: per-row sums, one WAVE per row ----------------
// part_s[row] = (sum_l, sumsq_l, sum_r, sumsq_r) over the row's 1024 elems.
// No barriers, 8 independent 16B loads per lane issued up front.
__global__ __launch_bounds__(256) void stats_kernel(const float* __restrict__ L,
                                                    const float* __restrict__ R,
                                                    float4* __restrict__ part_s) {
    const int wave = threadIdx.x >> 6;
    const int lane = threadIdx.x & 63;
    const int row = blockIdx.x * 4 + wave;          // grid = NROWS/4 blocks
    const float4* L4 = (const float4*)L;
    const float4* R4 = (const float4*)R;
    const size_t base = (size_t)row * 256 + lane;   // row = 256 float4s

    float4 l0 = L4[base      ];
    float4 l1 = L4[base +  64];
    float4 l2 = L4[base + 128];
    float4 l3 = L4[base + 192];
    float4 r0 = R4[base      ];
    float4 r1 = R4[base +  64];
    float4 r2 = R4[base + 128];
    float4 r3 = R4[base + 192];

    float sl = (l0.x + l0.y + l0.z + l0.w) + (l1.x + l1.y + l1.z + l1.w)
             + (l2.x + l2.y + l2.z + l2.w) + (l3.x + l3.y + l3.z + l3.w);
    float ql = (l0.x*l0.x + l0.y*l0.y + l0.z*l0.z + l0.w*l0.w)
             + (l1.x*l1.x + l1.y*l1.y + l1.z*l1.z + l1.w*l1.w)
             + (l2.x*l2.x + l2.y*l2.y + l2.z*l2.z + l2.w*l2.w)
             + (l3.x*l3.x + l3.y*l3.y + l3.z*l3.z + l3.w*l3.w);
    float sr = (r0.x + r0.y + r0.z + r0.w) + (r1.x + r1.y + r1.z + r1.w)
             + (r2.x + r2.y + r2.z + r2.w) + (r3.x + r3.y + r3.z + r3.w);
    float qr = (r0.x*r0.x + r0.y*r0.y + r0.z*r0.z + r0.w*r0.w)
             + (r1.x*r1.x + r1.y*r1.y + r1.z*r1.z + r1.w*r1.w)
             + (r2.x*r2.x + r2.y*r2.y + r2.z*r2.z + r2.w*r2.w)
             + (r3.x*r3.x + r3.y*r3.y + r3.z*r3.z + r3.w*r3.w);

#pragma unroll
    for (int off = 32; off > 0; off >>= 1) {
        sl += __shfl_down(sl, off);
        ql += __shfl_down(ql, off);
        sr += __shfl_down(sr, off);
        qr += __shfl_down(qr, off);
    }
    if (lane == 0) part_s[row] = make_float4(sl, ql, sr, qr);
}

// ------- Kernel 2: coef-from-partials + partial diff2 per channel-chunk -----
// part4[chunk][bt][hw] = sum_{c in chunk} (a_l x_l - a_r x_r - off)^2
__global__ __launch_bounds__(256) void diff2_kernel(const float* __restrict__ L,
                                                    const float* __restrict__ R,
                                                    const float4* __restrict__ part_s,
                                                    const float* __restrict__ gamma,
                                                    float4* __restrict__ part4) {
    const int chunk = blockIdx.x;   // 0..NCHUNK-1
    const int bt = blockIdx.y;      // b*T_ + t
    const int t = bt & (T_ - 1);
    const int tid = threadIdx.x;
    const int c0 = chunk * CCH;

    __shared__ float4 spart[B_][CCH];
    __shared__ float4 cf[CCH];

    if (tid < B_ * CCH) {           // 128 threads gather the b-partials
        int bg = tid >> 4, ci = tid & (CCH - 1);
        spart[bg][ci] = part_s[(bg * T_ + t) * C_ + c0 + ci];
    }
    __syncthreads();
    if (tid < CCH) {
        float S = 0.f, Q = 0.f, Sr = 0.f, Qr = 0.f;
#pragma unroll
        for (int bg = 0; bg < B_; ++bg) {
            float4 v = spart[bg][tid];
            S += v.x; Q += v.y; Sr += v.z; Qr += v.w;
        }
        const float inv = 1.0f / (float)(B_ * HW_);
        float mul = S * inv, mur = Sr * inv;
        float varl = Q * inv - mul * mul;
        float varr = Qr * inv - mur * mur;
        float s_l = rsqrtf(varl + EPS_);
        float s_r = rsqrtf(varr + EPS_);
        float g = gamma[c0 + tid];
        cf[tid] = make_float4(g * s_l, g * s_r, g * (s_l * mul - s_r * mur), 0.f);
    }
    __syncthreads();

    const float4* L4 = (const float4*)L;
    const float4* R4 = (const float4*)R;
    const size_t base4 = ((size_t)bt * C_ + c0) * (HW_ / 4);

    float a0 = 0.f, a1 = 0.f, a2 = 0.f, a3 = 0.f;
#pragma unroll
    for (int cc = 0; cc < CCH; cc += 4) {
        // 8 independent loads in flight per iteration
        float4 vl0 = L4[base4 + (cc + 0) * (HW_ / 4) + tid];
        float4 vl1 = L4[base4 + (cc + 1) * (HW_ / 4) + tid];
        float4 vl2 = L4[base4 + (cc + 2) * (HW_ / 4) + tid];
        float4 vl3 = L4[base4 + (cc + 3) * (HW_ / 4) + tid];
        float4 vr0 = R4[base4 + (cc + 0) * (HW_ / 4) + tid];
        float4 vr1 = R4[base4 + (cc + 1) * (HW_ / 4) + tid];
        float4 vr2 = R4[base4 + (cc + 2) * (HW_ / 4) + tid];
        float4 vr3 = R4[base4 + (cc + 3) * (HW_ / 4) + tid];
        float4 k0 = cf[cc + 0], k1 = cf[cc + 1], k2 = cf[cc + 2], k3 = cf[cc + 3];
        float d0, d1, d2, d3;
        d0 = k0.x*vl0.x - k0.y*vr0.x - k0.z; a0 += d0*d0;
        d1 = k0.x*vl0.y - k0.y*vr0.y - k0.z; a1 += d1*d1;
        d2 = k0.x*vl0.z - k0.y*vr0.z - k0.z; a2 += d2*d2;
        d3 = k0.x*vl0.w - k0.y*vr0.w - k0.z; a3 += d3*d3;
        d0 = k1.x*vl1.x - k1.y*vr1.x - k1.z; a0 += d0*d0;
        d1 = k1.x*vl1.y - k1.y*vr1.y - k1.z; a1 += d1*d1;
        d2 = k1.x*vl1.z - k1.y*vr1.z - k1.z; a2 += d2*d2;
        d3 = k1.x*vl1.w - k1.y*vr1.w - k1.z; a3 += d3*d3;
        d0 = k2.x*vl2.x - k2.y*vr2.x - k2.z; a0 += d0*d0;
        d1 = k2.x*vl2.y - k2.y*vr2.y - k2.z; a1 += d1*d1;
        d2 = k2.x*vl2.z - k2.y*vr2.z - k2.z; a2 += d2*d2;
        d3 = k2.x*vl2.w - k2.y*vr2.w - k2.z; a3 += d3*d3;
        d0 = k3.x*vl3.x - k3.y*vr3.x - k3.z; a0 += d0*d0;
        d1 = k3.x*vl3.y - k3.y*vr3.y - k3.z; a1 += d1*d1;
        d2 = k3.x*vl3.z - k3.y*vr3.z - k3.z; a2 += d2*d2;
        d3 = k3.x*vl3.w - k3.y*vr3.w - k3.z; a3 += d3*d3;
    }
    part4[((size_t)chunk * NBT + bt) * (HW_ / 4) + tid] = make_float4(a0, a1, a2, a3);
}

// ---------------- Kernel 3: sum partials, 5x5 windows, sqrt, max, argmin ----
// out layout (all f32): [0,32) asymmetry_values, [32,96) coords (x,y) pairs,
// [96, 96+32*784) heatmap.
__global__ __launch_bounds__(256) void finalize_kernel(const float4* __restrict__ part4,
                                                       float* __restrict__ out) {
    const int bt = blockIdx.x;
    const int tid = threadIdx.x;
    __shared__ float d[HW_];
    __shared__ float rowsum[32][HP_];
    __shared__ float rv[256];
    __shared__ int   ri[256];
    __shared__ float rmax[256];

    float4 s = make_float4(0.f, 0.f, 0.f, 0.f);
#pragma unroll
    for (int ch = 0; ch < NCHUNK; ++ch) {
        float4 v = part4[((size_t)ch * NBT + bt) * (HW_ / 4) + tid];
        s.x += v.x; s.y += v.y; s.z += v.z; s.w += v.w;
    }
    ((float4*)d)[tid] = s;
    __syncthreads();

    for (int i = tid; i < 32 * HP_; i += 256) {
        int h = i / HP_, w = i % HP_;
        const float* row = d + h * W_ + w;
        rowsum[h][w] = row[0] + row[1] + row[2] + row[3] + row[4];
    }
    __syncthreads();

    float lmax = -1e30f, lmin = 1e30f;
    int lidx = 0;
    for (int i = tid; i < HP_ * HP_; i += 256) {
        int hh = i / HP_, w = i % HP_;
        float ws = rowsum[hh][w] + rowsum[hh + 1][w] + rowsum[hh + 2][w] +
                   rowsum[hh + 3][w] + rowsum[hh + 4][w];
        float hm = sqrtf(ws * (1.0f / 25.0f));
        out[96 + (size_t)bt * (HP_ * HP_) + i] = hm;
        lmax = fmaxf(lmax, hm);
        if (hm < lmin) { lmin = hm; lidx = i; }  // i increasing -> first-min
    }
    rv[tid] = lmin; ri[tid] = lidx; rmax[tid] = lmax;
    __syncthreads();
    for (int st = 128; st > 0; st >>= 1) {
        if (tid < st) {
            float ov = rv[tid + st]; int oi = ri[tid + st];
            if (ov < rv[tid] || (ov == rv[tid] && oi < ri[tid])) { rv[tid] = ov; ri[tid] = oi; }
            rmax[tid] = fmaxf(rmax[tid], rmax[tid + st]);
        }
        __syncthreads();
    }
    if (tid == 0) {
        out[bt] = rmax[0];
        int idx = ri[0];
        out[32 + 2 * bt + 0] = (float)(idx % HP_);
        out[32 + 2 * bt + 1] = (float)(idx / HP_);
    }
}

extern "C" void kernel_launch(void* const* d_in, const int* in_sizes, int n_in,
                              void* d_out, int out_size, void* d_ws, size_t ws_size,
                              hipStream_t stream) {
    const float* L = (const float*)d_in[0];
    const float* R = (const float*)d_in[1];
    const float* gamma = (const float*)d_in[2];
    // d_in[3] = beta: cancels algebraically in (l - r), unused.
    float* out = (float*)d_out;

    // ws layout: part_s 16384 float4 (256 KB) | part4 32*32*1024 f32 (4 MB)
    float4* part_s = (float4*)d_ws;
    float4* part4 = (float4*)((char*)d_ws + sizeof(float4) * NROWS);

    stats_kernel<<<NROWS / 4, 256, 0, stream>>>(L, R, part_s);
    diff2_kernel<<<dim3(NCHUNK, NBT), 256, 0, stream>>>(L, R, part_s, gamma, part4);
    finalize_kernel<<<NBT, 256, 0, stream>>>(part4, out);
}